// Round 4
// baseline (764.606 us; speedup 1.0000x reference)
//
#include <hip/hip_runtime.h>
#include <stdint.h>

// Problem constants (fixed by setup_inputs).
constexpr int NPTS = 8192;
constexpr int DIM  = 64;
constexpr int KNN  = 12;

// dz_main tiling: 64x64 tile per WG (4 waves x 32x32 MFMA), 8 column splits.
constexpr int RT = 64;               // rows per workgroup
constexpr int CT = 64;               // cols per chunk
constexpr int CS = 8;                // column splits (grid parallelism)
constexpr int STRIPE = NPTS / CS;    // 1024 cols per split
constexpr int NCHUNK = STRIPE / CT;  // 16 chunks
constexpr int LSTR = 72;             // bf16 tile stride (144 B = 9*16: b128-aligned)
constexpr int SSTR = 68;             // d2 tile stride in floats (272 B, 16B-aligned)

constexpr unsigned long long SENTINEL = 0xFFFFFFFFFFFFFFFFull;

typedef short bf16x8 __attribute__((ext_vector_type(8)));
typedef float f32x4  __attribute__((ext_vector_type(4)));

__device__ __forceinline__ unsigned short f2bf(float x) {  // RNE f32->bf16
  unsigned u = __float_as_uint(x);
  return (unsigned short)((u + 0x7FFFu + ((u >> 16) & 1u)) >> 16);
}
__device__ __forceinline__ float bf2f(unsigned short h) {
  return __uint_as_float(((unsigned)h) << 16);
}

// Zero d_out (poisoned every call) and the per-row edge counters.
__global__ __launch_bounds__(256) void init_kernel(float* out, int* ecnt) {
  int g = blockIdx.x * 256 + threadIdx.x;
  if (g < NPTS) ecnt[g] = 0;
  if (g < 4) out[g] = 0.0f;
}

// latent fp32 -> (hi,lo) bf16 split arrays + row sumsq. One thread per row.
__global__ __launch_bounds__(256) void conv_kernel(
    const float* __restrict__ latent, unsigned short* __restrict__ Lh,
    unsigned short* __restrict__ Ll, float* __restrict__ sq) {
  int i = blockIdx.x * 256 + threadIdx.x;
  const float4* p = reinterpret_cast<const float4*>(latent + (size_t)i * DIM);
  float s = 0.f;
#pragma unroll
  for (int t = 0; t < DIM / 4; ++t) {
    float4 v = p[t];
    s += v.x * v.x + v.y * v.y + v.z * v.z + v.w * v.w;
    ushort4 h, l;
    h.x = f2bf(v.x); l.x = f2bf(v.x - bf2f(h.x));
    h.y = f2bf(v.y); l.y = f2bf(v.y - bf2f(h.y));
    h.z = f2bf(v.z); l.z = f2bf(v.z - bf2f(h.z));
    h.w = f2bf(v.w); l.w = f2bf(v.w - bf2f(h.w));
    *reinterpret_cast<ushort4*>(Lh + (size_t)i * DIM + t * 4) = h;
    *reinterpret_cast<ushort4*>(Ll + (size_t)i * DIM + t * 4) = l;
  }
  sq[i] = s;
}

// Stream mask_X coalesced at full BW; compress to per-row edge lists
// (col index + dist_X value). Exactly KNN nonzeros per row by construction.
__global__ __launch_bounds__(256) void scan_mask(
    const float* __restrict__ mask_X, const float* __restrict__ dist_X,
    int* __restrict__ ecnt, int* __restrict__ ecol, float* __restrict__ edx) {
  const int total4 = NPTS * NPTS / 4;
  int stride = gridDim.x * 256;
  for (int idx4 = blockIdx.x * 256 + threadIdx.x; idx4 < total4; idx4 += stride) {
    float4 m = reinterpret_cast<const float4*>(mask_X)[idx4];
    if (m.x == 0.f && m.y == 0.f && m.z == 0.f && m.w == 0.f) continue;
    int base = idx4 * 4;
    float mv[4] = {m.x, m.y, m.z, m.w};
#pragma unroll
    for (int c = 0; c < 4; ++c) {
      if (mv[c] != 0.f) {
        int pos = base + c;
        int i = pos >> 13, j = pos & (NPTS - 1);
        int slot = atomicAdd(&ecnt[i], 1);
        if (slot < KNN) {
          ecol[i * KNN + slot] = j;
          edx[i * KNN + slot] = dist_X[pos];
        }
      }
    }
  }
}

// Sorted-ascending 12-list insert; cand packs (d2_bits<<32)|j so u64 compare
// == (value, index) lexicographic == JAX stable argsort order.
__device__ __forceinline__ void topk_insert(unsigned long long cand,
                                            unsigned long long pk[KNN]) {
#pragma unroll
  for (int s = KNN - 1; s >= 0; --s) {
    bool belongs = cand < pk[s];
    bool shift = (s > 0) && (cand < pk[s - 1]);
    unsigned long long nv = shift ? pk[s - 1] : cand;
    if (belongs) pk[s] = nv;
  }
}

// Gram + top-k, queue-free. Per chunk: MFMA -> d2 tile in LDS -> each thread
// scans its quarter-row into a REGISTER top-12 (no atomics, no serial merge).
__global__ __launch_bounds__(256, 2) void dz_main(
    const unsigned short* __restrict__ Lh, const unsigned short* __restrict__ Ll,
    const float* __restrict__ sq, unsigned long long* __restrict__ topk_ws) {
  __shared__ __align__(16) char smem[54784];
  unsigned short* Ah = (unsigned short*)smem;            // 64x72 bf16-hi A
  unsigned short* Al = Ah + RT * LSTR;                   // 64x72 bf16-lo A
  unsigned short* Bh = Al + RT * LSTR;                   // 64x72 bf16-hi B
  unsigned short* Bl = Bh + CT * LSTR;                   // 64x72 bf16-lo B
  float* Sc  = (float*)(smem + 4 * RT * LSTR * 2);       // 64x68 d2 tile
  float* sqA = (float*)(smem + 4 * RT * LSTR * 2 + RT * SSTR * 4);
  float* sqB = sqA + RT;
  // Phase-2 overlay on the A/B region: 64 rows x 4 lanes x 12 u64 = 24 KB.
  unsigned long long* mb = (unsigned long long*)smem;

  const int tid = threadIdx.x;
  const int tile = blockIdx.x / CS;
  const int split = blockIdx.x % CS;
  const int ib = tile * RT;
  const int jb0 = split * STRIPE;

  const int wid = tid >> 6;
  const int lane = tid & 63;
  const int quad = lane >> 4;
  const int l16 = lane & 15;
  const int wr = wid >> 1;   // wave row-block (32 rows)
  const int wc = wid & 1;    // wave col-block (32 cols)

  // Scan-phase ownership: thread owns quarter-row (rl, cols qc*16..qc*16+15).
  const int srl = tid >> 2;
  const int sqc = tid & 3;

  // Stage A tile once: pure uint4 copies (64 rows x 8 chunks of 16B).
#pragma unroll
  for (int it = 0; it < 2; ++it) {
    int f = it * 256 + tid;  // 0..511
    int r = f >> 3, c = f & 7;
    *reinterpret_cast<uint4*>(&Ah[r * LSTR + c * 8]) =
        *reinterpret_cast<const uint4*>(Lh + (size_t)(ib + r) * DIM + c * 8);
    *reinterpret_cast<uint4*>(&Al[r * LSTR + c * 8]) =
        *reinterpret_cast<const uint4*>(Ll + (size_t)(ib + r) * DIM + c * 8);
  }
  if (tid < RT) sqA[tid] = sq[ib + tid];

  unsigned long long pk[KNN];
#pragma unroll
  for (int t = 0; t < KNN; ++t) pk[t] = SENTINEL;

  for (int ch = 0; ch < NCHUNK; ++ch) {
    const int jb = jb0 + ch * CT;
    __syncthreads();  // (A) prev scan done (Sc free), prev MFMA done (B free)
#pragma unroll
    for (int it = 0; it < 2; ++it) {
      int f = it * 256 + tid;
      int r = f >> 3, c = f & 7;
      *reinterpret_cast<uint4*>(&Bh[r * LSTR + c * 8]) =
          *reinterpret_cast<const uint4*>(Lh + (size_t)(jb + r) * DIM + c * 8);
      *reinterpret_cast<uint4*>(&Bl[r * LSTR + c * 8]) =
          *reinterpret_cast<const uint4*>(Ll + (size_t)(jb + r) * DIM + c * 8);
    }
    if (tid < CT) sqB[tid] = sq[jb + tid];
    __syncthreads();  // (B) staging visible

    // Gram via split-bf16 MFMA: hi*hi + hi*lo + lo*hi (~5e-6 rel err on d2).
    f32x4 acc[2][2];
#pragma unroll
    for (int rb = 0; rb < 2; ++rb)
#pragma unroll
      for (int cb = 0; cb < 2; ++cb) acc[rb][cb] = (f32x4){0.f, 0.f, 0.f, 0.f};

#pragma unroll
    for (int kk = 0; kk < 2; ++kk) {  // K=64 in two K=32 MFMA steps
      const int ko = kk * 32 + quad * 8;
      bf16x8 ah[2], al[2], bh[2], bl[2];
#pragma unroll
      for (int rb = 0; rb < 2; ++rb) {
        int row = wr * 32 + rb * 16 + l16;
        ah[rb] = *reinterpret_cast<const bf16x8*>(&Ah[row * LSTR + ko]);
        al[rb] = *reinterpret_cast<const bf16x8*>(&Al[row * LSTR + ko]);
      }
#pragma unroll
      for (int cb = 0; cb < 2; ++cb) {
        int col = wc * 32 + cb * 16 + l16;
        bh[cb] = *reinterpret_cast<const bf16x8*>(&Bh[col * LSTR + ko]);
        bl[cb] = *reinterpret_cast<const bf16x8*>(&Bl[col * LSTR + ko]);
      }
#pragma unroll
      for (int rb = 0; rb < 2; ++rb)
#pragma unroll
        for (int cb = 0; cb < 2; ++cb) {
          acc[rb][cb] = __builtin_amdgcn_mfma_f32_16x16x32_bf16(ah[rb], bh[cb], acc[rb][cb], 0, 0, 0);
          acc[rb][cb] = __builtin_amdgcn_mfma_f32_16x16x32_bf16(ah[rb], bl[cb], acc[rb][cb], 0, 0, 0);
          acc[rb][cb] = __builtin_amdgcn_mfma_f32_16x16x32_bf16(al[rb], bh[cb], acc[rb][cb], 0, 0, 0);
        }
    }

    // Epilogue: d2 (clamped; diagonal -> +huge) into the LDS tile.
    // C/D layout (verified): col = lane&15, row = quad*4 + reg.
#pragma unroll
    for (int rb = 0; rb < 2; ++rb) {
      const int row0 = wr * 32 + rb * 16 + quad * 4;
#pragma unroll
      for (int r = 0; r < 4; ++r) {
        const int rl = row0 + r;
        const float sa = sqA[rl];
        const int gi = ib + rl;
#pragma unroll
        for (int cb = 0; cb < 2; ++cb) {
          const int col_l = wc * 32 + cb * 16 + l16;
          const int gj = jb + col_l;
          float d2 = sa + sqB[col_l] - 2.0f * acc[rb][cb][r];
          float d2c = fmaxf(d2, 0.0f);
          Sc[rl * SSTR + col_l] = (gj == gi) ? 3.0e38f : d2c;
        }
      }
    }
    __syncthreads();  // (C) Sc visible

    // Scan: each thread owns 16 consecutive d2 of one row -> register top-12.
    const int cbase = jb + sqc * 16;
#pragma unroll
    for (int s = 0; s < 16; s += 4) {
      float4 v = *reinterpret_cast<const float4*>(&Sc[srl * SSTR + sqc * 16 + s]);
      float va[4] = {v.x, v.y, v.z, v.w};
#pragma unroll
      for (int c = 0; c < 4; ++c) {
        unsigned long long cand =
            ((unsigned long long)__float_as_uint(va[c]) << 32) |
            (unsigned)(cbase + s + c);
        if (cand < pk[KNN - 1]) topk_insert(cand, pk);
      }
    }
  }

  // Final: merge the 4 quarter-row lists per row (once), emit per-split top-12.
  __syncthreads();  // last MFMA/scan done; A/B region reusable as merge buffer
#pragma unroll
  for (int t = 0; t < KNN; ++t) mb[tid * KNN + t] = pk[t];  // (rl*4+qc)*12
  __syncthreads();
  if (tid < RT) {
    unsigned long long fk[KNN];
#pragma unroll
    for (int t = 0; t < KNN; ++t) fk[t] = SENTINEL;
    const unsigned long long* src = mb + tid * 4 * KNN;
    for (int t = 0; t < 4 * KNN; ++t) {
      unsigned long long cand = src[t];
      if (cand < fk[KNN - 1]) topk_insert(cand, fk);
    }
    size_t base = ((size_t)(ib + tid) * CS + split) * KNN;
#pragma unroll
    for (int t = 0; t < KNN; ++t) topk_ws[base + t] = fk[t];
  }
}

// distance1_2 over the 98K X-edges: dz from an exact fp32 dot on latent.
__global__ __launch_bounds__(256) void sig1_kernel(
    const float* __restrict__ latent, const float* __restrict__ latent_norm,
    const int* __restrict__ ecol, const float* __restrict__ edx,
    float* __restrict__ d_out) {
  __shared__ float red[256];
  const int tid = threadIdx.x;
  const int e = blockIdx.x * 256 + tid;  // e < NPTS*KNN exactly
  const float invnorm = 1.0f / latent_norm[0];

  int i = e / KNN;
  int j = ecol[e];
  float dx = edx[e];
  const float4* a = reinterpret_cast<const float4*>(latent + (size_t)i * DIM);
  const float4* b = reinterpret_cast<const float4*>(latent + (size_t)j * DIM);
  float d2 = 0.f;
#pragma unroll
  for (int t = 0; t < DIM / 4; ++t) {
    float4 va = a[t], vb = b[t];
    float ex = va.x - vb.x, ey = va.y - vb.y, ez = va.z - vb.z, ew = va.w - vb.w;
    d2 += ex * ex + ey * ey + ez * ez + ew * ew;
  }
  float dz = (d2 > 0.f) ? sqrtf(d2) * invnorm : 0.f;
  float diff = dx - dz;

  red[tid] = diff * diff;
  __syncthreads();
  for (int s = 128; s > 0; s >>= 1) {
    if (tid < s) red[tid] += red[tid + s];
    __syncthreads();
  }
  if (tid == 0) {
    atomicAdd(&d_out[2], red[0]);
    atomicAdd(&d_out[0], red[0]);
  }
}

// Merge the CS partial top-12 lists per row; distance2_1 + matched count.
__global__ __launch_bounds__(256) void finalize_kernel(
    const float* __restrict__ latent_norm, const float* __restrict__ dist_X,
    const int* __restrict__ ecol, const unsigned long long* __restrict__ topk_ws,
    float* __restrict__ d_out) {
  __shared__ float red[256];
  const int tid = threadIdx.x;
  const int gi = blockIdx.x * 256 + tid;
  const float invnorm = 1.0f / latent_norm[0];

  unsigned long long pk[KNN];
#pragma unroll
  for (int t = 0; t < KNN; ++t) pk[t] = SENTINEL;

  const unsigned long long* src = topk_ws + (size_t)gi * CS * KNN;
  for (int t = 0; t < CS * KNN; ++t) {
    unsigned long long cand = src[t];
    if (cand < pk[KNN - 1]) topk_insert(cand, pk);
  }

  int ec[KNN];
#pragma unroll
  for (int t = 0; t < KNN; ++t) ec[t] = ecol[gi * KNN + t];

  float acc2 = 0.f, accc = 0.f;
#pragma unroll
  for (int t = 0; t < KNN; ++t) {
    int j = (int)(unsigned)(pk[t] & 0xFFFFFFFFull);
    float d2 = __uint_as_float((unsigned)(pk[t] >> 32));
    float dz = (d2 > 0.0f) ? sqrtf(d2) * invnorm : 0.0f;
    float dxv = dist_X[(size_t)gi * NPTS + j];
    float diff = dxv - dz;
    acc2 += diff * diff;
    int hit = 0;
#pragma unroll
    for (int s = 0; s < KNN; ++s) hit |= (ec[s] == j);
    accc += (float)hit;  // Z-edge also present in X-mask
  }

  red[tid] = acc2;
  __syncthreads();
  for (int s = 128; s > 0; s >>= 1) {
    if (tid < s) red[tid] += red[tid + s];
    __syncthreads();
  }
  float racc2 = red[0];
  __syncthreads();
  red[tid] = accc;
  __syncthreads();
  for (int s = 128; s > 0; s >>= 1) {
    if (tid < s) red[tid] += red[tid + s];
    __syncthreads();
  }
  if (tid == 0) {
    atomicAdd(&d_out[3], racc2);
    atomicAdd(&d_out[0], racc2);
    atomicAdd(&d_out[1], red[0] * (1.0f / ((float)NPTS * (float)KNN)));
  }
}

extern "C" void kernel_launch(void* const* d_in, const int* in_sizes, int n_in,
                              void* d_out, int out_size, void* d_ws,
                              size_t ws_size, hipStream_t stream) {
  const float* latent      = (const float*)d_in[0];
  const float* latent_norm = (const float*)d_in[1];
  const float* dist_X      = (const float*)d_in[2];
  const float* mask_X      = (const float*)d_in[3];
  float* out = (float*)d_out;

  // Workspace layout (all 16B-aligned).
  char* w = (char*)d_ws;
  float*          sq   = (float*)w;                    w += NPTS * 4;
  unsigned short* Lh   = (unsigned short*)w;           w += NPTS * DIM * 2;
  unsigned short* Ll   = (unsigned short*)w;           w += NPTS * DIM * 2;
  int*            ecnt = (int*)w;                      w += NPTS * 4;
  int*            ecol = (int*)w;                      w += NPTS * KNN * 4;
  float*          edx  = (float*)w;                    w += NPTS * KNN * 4;
  unsigned long long* topk = (unsigned long long*)w;   // 8192*8*12*8 = 6.3 MB

  init_kernel<<<NPTS / 256, 256, 0, stream>>>(out, ecnt);
  conv_kernel<<<NPTS / 256, 256, 0, stream>>>(latent, Lh, Ll, sq);
  scan_mask<<<2048, 256, 0, stream>>>(mask_X, dist_X, ecnt, ecol, edx);
  dz_main<<<(NPTS / RT) * CS, 256, 0, stream>>>(Lh, Ll, sq, topk);
  sig1_kernel<<<NPTS * KNN / 256, 256, 0, stream>>>(latent, latent_norm, ecol,
                                                    edx, out);
  finalize_kernel<<<NPTS / 256, 256, 0, stream>>>(latent_norm, dist_X, ecol,
                                                  topk, out);
}